// Round 21
// baseline (309.588 us; speedup 1.0000x reference)
//
#include <hip/hip_runtime.h>
#include <hip/hip_bf16.h>
#include <math.h>

#define NNODES 50000
#define NEDGES 800000
#define CHUNKS (NEDGES / 64)     // 12500 chunks of 64 CSR slots (or edges)
#define NBLK 256
#define GWAVES (NBLK * 8)        // 2048 persistent waves (512-thr blocks)

using short8 = __attribute__((ext_vector_type(8))) short;   // 8 bf16 = 4 VGPRs
using f32x4  = __attribute__((ext_vector_type(4))) float;
using f32x16 = __attribute__((ext_vector_type(16))) float;  // 32x32 MFMA acc
using u32x4  = __attribute__((ext_vector_type(4))) unsigned;

__device__ __forceinline__ short f2b(float v) {
    return __builtin_bit_cast(short, __float2bfloat16(v));
}
__device__ __forceinline__ unsigned cvt2(float a, float b) {
    return (unsigned)(unsigned short)f2b(a) | ((unsigned)(unsigned short)f2b(b) << 16);
}
__device__ __forceinline__ float b2f_lo(unsigned u) {
    return __builtin_bit_cast(float, u << 16);
}
__device__ __forceinline__ float b2f_hi(unsigned u) {
    return __builtin_bit_cast(float, u & 0xFFFF0000u);
}

// ---- merged prep: x->bf16, W pack (32x32 A-frag order), CSR count ----
__global__ void prep_all(const float* __restrict__ x, short* __restrict__ xb,
                         const float* __restrict__ W1, const float* __restrict__ W2,
                         short* __restrict__ wpk, const int* __restrict__ ei,
                         unsigned* __restrict__ cnt)
{
    int b = blockIdx.x;
    if (b < 3125) {
        int i = b * 256 + threadIdx.x;
        float4 v = reinterpret_cast<const float4*>(x)[i];
        short4 o;
        o.x = f2b(v.x); o.y = f2b(v.y); o.z = f2b(v.z); o.w = f2b(v.w);
        reinterpret_cast<short4*>(xb)[i] = o;
    } else if (b < 6250) {
        int e = (b - 3125) * 256 + threadIdx.x;
        atomicAdd(&cnt[ei[e]], 1u);
    } else {
        int i = (b - 6250) * 256 + threadIdx.x;
        if (i < 40960) {                  // W1 [k<160][n<256]
            int k = i >> 8, n = i & 255;
            int lane = (n & 31) + (((k >> 3) & 1) << 5);
            wpk[(((n >> 5) * 10 + (k >> 4)) * 64 + lane) * 8 + (k & 7)] = f2b(W1[i]);
        }
        if (i < 16384) {                  // W2 [k<256][n<64]
            int k = i >> 6, n = i & 63;
            int lane = (n & 31) + (((k >> 3) & 1) << 5);
            wpk[40960 + (((n >> 5) * 16 + (k >> 4)) * 64 + lane) * 8 + (k & 7)] = f2b(W2[i]);
        }
    }
}

// ---- CSR scan: per-block inclusive scan; LAST block also scans bsum ----
__global__ __launch_bounds__(1024)
void csr_scan1(const unsigned* __restrict__ cnt, unsigned* __restrict__ offs,
               unsigned* __restrict__ bsum, unsigned* __restrict__ done) {
    __shared__ unsigned sbuf[1024];
    __shared__ unsigned ticket;
    int t = threadIdx.x, i = blockIdx.x * 1024 + t;
    unsigned v = (i < NNODES) ? cnt[i] : 0u;
    sbuf[t] = v;
    __syncthreads();
    for (int off = 1; off < 1024; off <<= 1) {
        unsigned add = (t >= off) ? sbuf[t - off] : 0u;
        __syncthreads();
        sbuf[t] += add;
        __syncthreads();
    }
    if (i < NNODES) offs[i] = sbuf[t];
    if (t == 1023) bsum[blockIdx.x] = sbuf[1023];
    __threadfence();                       // release our bsum write
    __syncthreads();
    if (t == 0) ticket = atomicAdd(done, 1u);
    __syncthreads();
    if (ticket == 48u && t < 64) {         // last-done block: exclusive scan of 49
        __threadfence();                   // acquire all blocks' bsum writes
        unsigned v2 = (t < 49) ? bsum[t] : 0u;
        unsigned orig = v2;
        for (int off = 1; off < 64; off <<= 1) {
            unsigned n = __shfl_up(v2, off, 64);
            if (t >= off) v2 += n;
        }
        if (t < 49) bsum[t] = v2 - orig;
    }
}

__global__ __launch_bounds__(1024)
void csr_scan3(const unsigned* __restrict__ cnt, unsigned* __restrict__ offs,
               const unsigned* __restrict__ bsum) {
    int i = blockIdx.x * 1024 + threadIdx.x;
    if (i < NNODES)       offs[i] = offs[i] - cnt[i] + bsum[blockIdx.x];
    else if (i == NNODES) offs[i] = NEDGES;
}

// place: also record (r, cc) per CSR slot so main's index reads are coalesced
__global__ void csr_place(const int* __restrict__ ei, const unsigned* __restrict__ offs,
                          unsigned* __restrict__ cur, unsigned* __restrict__ elist,
                          uint2* __restrict__ rc2) {
    int e = blockIdx.x * 256 + threadIdx.x;
    if (e < NEDGES) {
        int r = ei[e], cc = ei[NEDGES + e];
        unsigned p = offs[r] + atomicAdd(&cur[r], 1u);
        elist[p] = (unsigned)e;
        if (rc2) { uint2 v; v.x = (unsigned)r; v.y = (unsigned)cc; rc2[p] = v; }
    }
}

// ---- main (big path): CSR-ordered chunks, R15 math, contiguous bf16 shadow ----
__global__ __launch_bounds__(512, 2)
void edgeconv_csr(const short* __restrict__ xb, const float* __restrict__ ea,
                  const short* __restrict__ wpk, const float* __restrict__ b1,
                  const float* __restrict__ b2, const unsigned* __restrict__ elist,
                  const uint2* __restrict__ rc2, float* __restrict__ outbuf,
                  unsigned* __restrict__ outcsr)
{
    __shared__ short    wlds[57344];     // 112 KB: W1/W2 fragments
    __shared__ unsigned tb[8][1280];     //  40 KB: per-wave 32x(40-dword) transpose tile

    for (int i = threadIdx.x; i < 7168; i += 512)
        reinterpret_cast<short8*>(wlds)[i] = reinterpret_cast<const short8*>(wpk)[i];
    __syncthreads();                     // only block-wide barrier

    const short* w1s = wlds;
    const short* w2s = wlds + 40960;
    const int lane = threadIdx.x & 63;
    const int wave = threadIdx.x >> 6;
    const int l32 = lane & 31, hi = lane >> 5;
    unsigned* tw = tb[wave];
    const int gw = blockIdx.x * 8 + wave;

    // prime indices (coalesced)
    int eo0 = 0, eo1 = 0, r0 = 0, r1 = 0, c0 = 0, c1 = 0;
    if (gw < CHUNKS) {
        int p0 = gw * 64 + l32, p1 = p0 + 32;
        eo0 = (int)elist[p0]; eo1 = (int)elist[p1];
        uint2 a = rc2[p0], b = rc2[p1];
        r0 = (int)a.x; c0 = (int)a.y;
        r1 = (int)b.x; c1 = (int)b.y;
    }

    for (int c = gw; c < CHUNKS; c += GWAVES) {
        // prefetch next chunk's indices
        int cnx = c + GWAVES;
        int eo0n = 0, eo1n = 0, r0n = 0, r1n = 0, c0n = 0, c1n = 0;
        if (cnx < CHUNKS) {
            int p0 = cnx * 64 + l32, p1 = p0 + 32;
            eo0n = (int)elist[p0]; eo1n = (int)elist[p1];
            uint2 a = rc2[p0], b = rc2[p1];
            r0n = (int)a.x; c0n = (int)a.y;
            r1n = (int)b.x; c1n = (int)b.y;
        }

        // gather B-fragments: k = ks*16 + hi*8 + j
        short8 fx[2][10];
        #pragma unroll
        for (int g = 0; g < 2; ++g) {
            const int rr = g ? r1 : r0, cg = g ? c1 : c0;
            const int eo = g ? eo1 : eo0;
            #pragma unroll
            for (int ks = 0; ks < 4; ++ks)
                fx[g][ks] = *reinterpret_cast<const short8*>(xb + rr * 64 + ks * 16 + hi * 8);
            #pragma unroll
            for (int ks = 0; ks < 4; ++ks)
                fx[g][4 + ks] = *reinterpret_cast<const short8*>(xb + cg * 64 + ks * 16 + hi * 8);
            #pragma unroll
            for (int ks = 0; ks < 2; ++ks) {
                const float4* p = reinterpret_cast<const float4*>(ea + (size_t)eo * 32 + ks * 16 + hi * 8);
                float4 a = p[0], b = p[1];
                u32x4 uu;
                uu[0] = cvt2(a.x, a.y); uu[1] = cvt2(a.z, a.w);
                uu[2] = cvt2(b.x, b.y); uu[3] = cvt2(b.z, b.w);
                fx[g][8 + ks] = __builtin_bit_cast(short8, uu);
            }
        }

        // acc2 init = b2
        f32x16 acc2[2][2];
        #pragma unroll
        for (int t2 = 0; t2 < 2; ++t2)
            #pragma unroll
            for (int gg = 0; gg < 4; ++gg) {
                float4 bb = *reinterpret_cast<const float4*>(b2 + t2 * 32 + gg * 8 + hi * 4);
                #pragma unroll
                for (int g = 0; g < 2; ++g) {
                    acc2[t2][g][gg * 4 + 0] = bb.x; acc2[t2][g][gg * 4 + 1] = bb.y;
                    acc2[t2][g][gg * 4 + 2] = bb.z; acc2[t2][g][gg * 4 + 3] = bb.w;
                }
            }

        #pragma unroll 1
        for (int t = 0; t < 8; ++t) {    // 8 H-tiles of 32 cols
            f32x16 acc1[2];
            #pragma unroll
            for (int gg = 0; gg < 4; ++gg) {
                float4 bb = *reinterpret_cast<const float4*>(b1 + t * 32 + gg * 8 + hi * 4);
                #pragma unroll
                for (int g = 0; g < 2; ++g) {
                    acc1[g][gg * 4 + 0] = bb.x; acc1[g][gg * 4 + 1] = bb.y;
                    acc1[g][gg * 4 + 2] = bb.z; acc1[g][gg * 4 + 3] = bb.w;
                }
            }
            #pragma unroll
            for (int ks = 0; ks < 10; ++ks) {
                short8 wf = *reinterpret_cast<const short8*>(
                    w1s + ((t * 10 + ks) * 64 + lane) * 8);
                acc1[0] = __builtin_amdgcn_mfma_f32_32x32x16_bf16(wf, fx[0][ks], acc1[0], 0, 0, 0);
                acc1[1] = __builtin_amdgcn_mfma_f32_32x32x16_bf16(wf, fx[1][ks], acc1[1], 0, 0, 0);
            }
            #pragma unroll
            for (int ksl = 0; ksl < 2; ++ksl) {
                int ks2 = t * 2 + ksl;
                short8 w20 = *reinterpret_cast<const short8*>(w2s + (ks2 * 64 + lane) * 8);
                short8 w21 = *reinterpret_cast<const short8*>(w2s + ((16 + ks2) * 64 + lane) * 8);
                #pragma unroll
                for (int g = 0; g < 2; ++g) {
                    int q0 = ksl * 8;
                    unsigned D0 = cvt2(fmaxf(acc1[g][q0 + 0], 0.f), fmaxf(acc1[g][q0 + 1], 0.f));
                    unsigned D1 = cvt2(fmaxf(acc1[g][q0 + 2], 0.f), fmaxf(acc1[g][q0 + 3], 0.f));
                    unsigned D2 = cvt2(fmaxf(acc1[g][q0 + 4], 0.f), fmaxf(acc1[g][q0 + 5], 0.f));
                    unsigned D3 = cvt2(fmaxf(acc1[g][q0 + 6], 0.f), fmaxf(acc1[g][q0 + 7], 0.f));
                    asm("v_permlane32_swap_b32 %0, %1" : "+v"(D0), "+v"(D2));
                    asm("v_permlane32_swap_b32 %0, %1" : "+v"(D1), "+v"(D3));
                    u32x4 bu; bu[0] = D0; bu[1] = D1; bu[2] = D2; bu[3] = D3;
                    short8 hb = __builtin_bit_cast(short8, bu);
                    acc2[0][g] = __builtin_amdgcn_mfma_f32_32x32x16_bf16(w20, hb, acc2[0][g], 0, 0, 0);
                    acc2[1][g] = __builtin_amdgcn_mfma_f32_32x32x16_bf16(w21, hb, acc2[1][g], 0, 0, 0);
                }
            }
        }

        // epilogue: f32 rows scattered to original edge id + contiguous bf16 shadow
        #pragma unroll
        for (int g = 0; g < 2; ++g) {
            const int eo = g ? eo1 : eo0;
            #pragma unroll
            for (int t2 = 0; t2 < 2; ++t2)
                #pragma unroll
                for (int gg = 0; gg < 4; ++gg) {
                    f32x4 v;
                    v[0] = acc2[t2][g][gg * 4 + 0]; v[1] = acc2[t2][g][gg * 4 + 1];
                    v[2] = acc2[t2][g][gg * 4 + 2]; v[3] = acc2[t2][g][gg * 4 + 3];
                    *reinterpret_cast<f32x4*>(outbuf + (size_t)eo * 64 + t2 * 32 + gg * 8 + hi * 4) = v;
                }
            // pack bf16 into per-wave LDS tile (row stride 40 dwords)
            #pragma unroll
            for (int t2 = 0; t2 < 2; ++t2)
                #pragma unroll
                for (int gg = 0; gg < 4; ++gg) {
                    uint2 w;
                    w.x = cvt2(acc2[t2][g][gg * 4 + 0], acc2[t2][g][gg * 4 + 1]);
                    w.y = cvt2(acc2[t2][g][gg * 4 + 2], acc2[t2][g][gg * 4 + 3]);
                    *reinterpret_cast<uint2*>(&tw[l32 * 40 + t2 * 16 + gg * 4 + hi * 2]) = w;
                }
            asm volatile("s_waitcnt lgkmcnt(0)" ::: "memory");
            // 4 fully-contiguous 1KB stores to CSR-contiguous shadow rows
            #pragma unroll
            for (int i = 0; i < 4; ++i) {
                int row = i * 8 + (lane >> 3);
                u32x4 v = *reinterpret_cast<const u32x4*>(&tw[row * 40 + (lane & 7) * 4]);
                *reinterpret_cast<u32x4*>(
                    outcsr + ((size_t)(c * 64 + g * 32) * 32) + i * 256 + lane * 4) = v;
            }
            asm volatile("" ::: "memory");
        }

        eo0 = eo0n; eo1 = eo1n; r0 = r0n; r1 = r1n; c0 = c0n; c1 = c1n;
    }
}

// ---- aggregate (big path): sequential bf16 rows, 16 rows in flight/wave ----
__global__ __launch_bounds__(256)
void agg_csr(const unsigned* __restrict__ offs, const unsigned* __restrict__ outcsr,
             float* __restrict__ agg)
{
    const int wave = threadIdx.x >> 6, lane = threadIdx.x & 63;
    const int l16 = lane & 15, qw = lane >> 4;
    const int node = blockIdx.x * 4 + wave;
    if (node >= NNODES) return;
    const unsigned s = offs[node], eend = offs[node + 1];
    float m0 = -INFINITY, m1 = -INFINITY, m2 = -INFINITY, m3 = -INFINITY;
    unsigned p = s + qw;
    for (; p + 12 < eend; p += 16) {     // 4 rows per qw in flight (16 total/wave)
        uint2 u0 = *reinterpret_cast<const uint2*>(outcsr + (size_t)p * 32 + l16 * 2);
        uint2 u1 = *reinterpret_cast<const uint2*>(outcsr + (size_t)(p + 4) * 32 + l16 * 2);
        uint2 u2 = *reinterpret_cast<const uint2*>(outcsr + (size_t)(p + 8) * 32 + l16 * 2);
        uint2 u3 = *reinterpret_cast<const uint2*>(outcsr + (size_t)(p + 12) * 32 + l16 * 2);
        m0 = fmaxf(fmaxf(fmaxf(m0, b2f_lo(u0.x)), fmaxf(b2f_lo(u1.x), b2f_lo(u2.x))), b2f_lo(u3.x));
        m1 = fmaxf(fmaxf(fmaxf(m1, b2f_hi(u0.x)), fmaxf(b2f_hi(u1.x), b2f_hi(u2.x))), b2f_hi(u3.x));
        m2 = fmaxf(fmaxf(fmaxf(m2, b2f_lo(u0.y)), fmaxf(b2f_lo(u1.y), b2f_lo(u2.y))), b2f_lo(u3.y));
        m3 = fmaxf(fmaxf(fmaxf(m3, b2f_hi(u0.y)), fmaxf(b2f_hi(u1.y), b2f_hi(u2.y))), b2f_hi(u3.y));
    }
    for (; p < eend; p += 4) {
        uint2 u = *reinterpret_cast<const uint2*>(outcsr + (size_t)p * 32 + l16 * 2);
        m0 = fmaxf(m0, b2f_lo(u.x)); m1 = fmaxf(m1, b2f_hi(u.x));
        m2 = fmaxf(m2, b2f_lo(u.y)); m3 = fmaxf(m3, b2f_hi(u.y));
    }
    m0 = fmaxf(m0, __shfl_xor(m0, 16, 64)); m1 = fmaxf(m1, __shfl_xor(m1, 16, 64));
    m2 = fmaxf(m2, __shfl_xor(m2, 16, 64)); m3 = fmaxf(m3, __shfl_xor(m3, 16, 64));
    m0 = fmaxf(m0, __shfl_xor(m0, 32, 64)); m1 = fmaxf(m1, __shfl_xor(m1, 32, 64));
    m2 = fmaxf(m2, __shfl_xor(m2, 32, 64)); m3 = fmaxf(m3, __shfl_xor(m3, 32, 64));
    if (qw == 0) {
        f32x4 o;
        bool emp = (s == eend);
        o[0] = emp ? 0.0f : m0; o[1] = emp ? 0.0f : m1;
        o[2] = emp ? 0.0f : m2; o[3] = emp ? 0.0f : m3;
        *reinterpret_cast<f32x4*>(agg + (size_t)node * 64 + l16 * 4) = o;
    }
}

// ==================== fallback path (exact R15) ====================
__global__ __launch_bounds__(512, 2)
void edgeconv_orig(const short* __restrict__ xb, const int* __restrict__ ei,
                   const float* __restrict__ ea, const short* __restrict__ wpk,
                   const float* __restrict__ b1, const float* __restrict__ b2,
                   float* __restrict__ outbuf)
{
    __shared__ short wlds[57344];
    for (int i = threadIdx.x; i < 7168; i += 512)
        reinterpret_cast<short8*>(wlds)[i] = reinterpret_cast<const short8*>(wpk)[i];
    __syncthreads();

    const short* w1s = wlds;
    const short* w2s = wlds + 40960;
    const int lane = threadIdx.x & 63;
    const int wave = threadIdx.x >> 6;
    const int l32 = lane & 31, hi = lane >> 5;
    const int gw = blockIdx.x * 8 + wave;

    int r0 = 0, r1 = 0, c0 = 0, c1 = 0;
    {
        int ea0 = gw * 64 + l32, ea1 = gw * 64 + 32 + l32;
        r0 = ei[ea0]; c0 = ei[NEDGES + ea0];
        r1 = ei[ea1]; c1 = ei[NEDGES + ea1];
    }
    for (int c = gw; c < CHUNKS; c += GWAVES) {
        int cnx = c + GWAVES;
        int r0n = 0, r1n = 0, c0n = 0, c1n = 0;
        if (cnx < CHUNKS) {
            int ea0 = cnx * 64 + l32, ea1 = cnx * 64 + 32 + l32;
            r0n = ei[ea0]; c0n = ei[NEDGES + ea0];
            r1n = ei[ea1]; c1n = ei[NEDGES + ea1];
        }
        short8 fx[2][10];
        #pragma unroll
        for (int g = 0; g < 2; ++g) {
            const int rr = g ? r1 : r0, cg = g ? c1 : c0;
            const int e = c * 64 + g * 32 + l32;
            #pragma unroll
            for (int ks = 0; ks < 4; ++ks)
                fx[g][ks] = *reinterpret_cast<const short8*>(xb + rr * 64 + ks * 16 + hi * 8);
            #pragma unroll
            for (int ks = 0; ks < 4; ++ks)
                fx[g][4 + ks] = *reinterpret_cast<const short8*>(xb + cg * 64 + ks * 16 + hi * 8);
            #pragma unroll
            for (int ks = 0; ks < 2; ++ks) {
                const float4* p = reinterpret_cast<const float4*>(ea + (size_t)e * 32 + ks * 16 + hi * 8);
                float4 a = p[0], b = p[1];
                u32x4 uu;
                uu[0] = cvt2(a.x, a.y); uu[1] = cvt2(a.z, a.w);
                uu[2] = cvt2(b.x, b.y); uu[3] = cvt2(b.z, b.w);
                fx[g][8 + ks] = __builtin_bit_cast(short8, uu);
            }
        }
        f32x16 acc2[2][2];
        #pragma unroll
        for (int t2 = 0; t2 < 2; ++t2)
            #pragma unroll
            for (int gg = 0; gg < 4; ++gg) {
                float4 bb = *reinterpret_cast<const float4*>(b2 + t2 * 32 + gg * 8 + hi * 4);
                #pragma unroll
                for (int g = 0; g < 2; ++g) {
                    acc2[t2][g][gg * 4 + 0] = bb.x; acc2[t2][g][gg * 4 + 1] = bb.y;
                    acc2[t2][g][gg * 4 + 2] = bb.z; acc2[t2][g][gg * 4 + 3] = bb.w;
                }
            }
        #pragma unroll 1
        for (int t = 0; t < 8; ++t) {
            f32x16 acc1[2];
            #pragma unroll
            for (int gg = 0; gg < 4; ++gg) {
                float4 bb = *reinterpret_cast<const float4*>(b1 + t * 32 + gg * 8 + hi * 4);
                #pragma unroll
                for (int g = 0; g < 2; ++g) {
                    acc1[g][gg * 4 + 0] = bb.x; acc1[g][gg * 4 + 1] = bb.y;
                    acc1[g][gg * 4 + 2] = bb.z; acc1[g][gg * 4 + 3] = bb.w;
                }
            }
            #pragma unroll
            for (int ks = 0; ks < 10; ++ks) {
                short8 wf = *reinterpret_cast<const short8*>(
                    w1s + ((t * 10 + ks) * 64 + lane) * 8);
                acc1[0] = __builtin_amdgcn_mfma_f32_32x32x16_bf16(wf, fx[0][ks], acc1[0], 0, 0, 0);
                acc1[1] = __builtin_amdgcn_mfma_f32_32x32x16_bf16(wf, fx[1][ks], acc1[1], 0, 0, 0);
            }
            #pragma unroll
            for (int ksl = 0; ksl < 2; ++ksl) {
                int ks2 = t * 2 + ksl;
                short8 w20 = *reinterpret_cast<const short8*>(w2s + (ks2 * 64 + lane) * 8);
                short8 w21 = *reinterpret_cast<const short8*>(w2s + ((16 + ks2) * 64 + lane) * 8);
                #pragma unroll
                for (int g = 0; g < 2; ++g) {
                    int q0 = ksl * 8;
                    unsigned D0 = cvt2(fmaxf(acc1[g][q0 + 0], 0.f), fmaxf(acc1[g][q0 + 1], 0.f));
                    unsigned D1 = cvt2(fmaxf(acc1[g][q0 + 2], 0.f), fmaxf(acc1[g][q0 + 3], 0.f));
                    unsigned D2 = cvt2(fmaxf(acc1[g][q0 + 4], 0.f), fmaxf(acc1[g][q0 + 5], 0.f));
                    unsigned D3 = cvt2(fmaxf(acc1[g][q0 + 6], 0.f), fmaxf(acc1[g][q0 + 7], 0.f));
                    asm("v_permlane32_swap_b32 %0, %1" : "+v"(D0), "+v"(D2));
                    asm("v_permlane32_swap_b32 %0, %1" : "+v"(D1), "+v"(D3));
                    u32x4 bu; bu[0] = D0; bu[1] = D1; bu[2] = D2; bu[3] = D3;
                    short8 hb = __builtin_bit_cast(short8, bu);
                    acc2[0][g] = __builtin_amdgcn_mfma_f32_32x32x16_bf16(w20, hb, acc2[0][g], 0, 0, 0);
                    acc2[1][g] = __builtin_amdgcn_mfma_f32_32x32x16_bf16(w21, hb, acc2[1][g], 0, 0, 0);
                }
            }
        }
        #pragma unroll
        for (int g = 0; g < 2; ++g) {
            const int e = c * 64 + g * 32 + l32;
            #pragma unroll
            for (int t2 = 0; t2 < 2; ++t2)
                #pragma unroll
                for (int gg = 0; gg < 4; ++gg) {
                    f32x4 v;
                    v[0] = acc2[t2][g][gg * 4 + 0]; v[1] = acc2[t2][g][gg * 4 + 1];
                    v[2] = acc2[t2][g][gg * 4 + 2]; v[3] = acc2[t2][g][gg * 4 + 3];
                    *reinterpret_cast<f32x4*>(outbuf + (size_t)e * 64 + t2 * 32 + gg * 8 + hi * 4) = v;
                }
        }
        r0 = r0n; r1 = r1n; c0 = c0n; c1 = c1n;
    }
}

__global__ __launch_bounds__(256)
void agg_list(const unsigned* __restrict__ offs, const unsigned* __restrict__ elist,
              const float* __restrict__ outbuf, float* __restrict__ agg)
{
    const int wave = threadIdx.x >> 6, lane = threadIdx.x & 63;
    const int node = blockIdx.x * 4 + wave;
    if (node >= NNODES) return;
    const unsigned s = offs[node], eend = offs[node + 1];
    float m0 = -INFINITY, m1 = -INFINITY, m2 = -INFINITY, m3 = -INFINITY;
    float m4 = -INFINITY, m5 = -INFINITY, m6 = -INFINITY, m7 = -INFINITY;
    unsigned p = s;
    for (; p + 8 <= eend; p += 8) {
        float a = outbuf[(size_t)elist[p + 0] * 64 + lane];
        float b = outbuf[(size_t)elist[p + 1] * 64 + lane];
        float c = outbuf[(size_t)elist[p + 2] * 64 + lane];
        float d = outbuf[(size_t)elist[p + 3] * 64 + lane];
        float e = outbuf[(size_t)elist[p + 4] * 64 + lane];
        float f = outbuf[(size_t)elist[p + 5] * 64 + lane];
        float g = outbuf[(size_t)elist[p + 6] * 64 + lane];
        float h = outbuf[(size_t)elist[p + 7] * 64 + lane];
        m0 = fmaxf(m0, a); m1 = fmaxf(m1, b); m2 = fmaxf(m2, c); m3 = fmaxf(m3, d);
        m4 = fmaxf(m4, e); m5 = fmaxf(m5, f); m6 = fmaxf(m6, g); m7 = fmaxf(m7, h);
    }
    for (; p < eend; ++p) m0 = fmaxf(m0, outbuf[(size_t)elist[p] * 64 + lane]);
    float m = fmaxf(fmaxf(fmaxf(m0, m1), fmaxf(m2, m3)),
                    fmaxf(fmaxf(m4, m5), fmaxf(m6, m7)));
    agg[(size_t)node * 64 + lane] = (s == eend) ? 0.0f : m;
}

extern "C" void kernel_launch(void* const* d_in, const int* in_sizes, int n_in,
                              void* d_out, int out_size, void* d_ws, size_t ws_size,
                              hipStream_t stream)
{
    const float* x  = (const float*)d_in[0];
    const int*   ei = (const int*)d_in[1];
    const float* ea = (const float*)d_in[2];
    const float* W1 = (const float*)d_in[3];
    const float* b1 = (const float*)d_in[4];
    const float* W2 = (const float*)d_in[5];
    const float* b2 = (const float*)d_in[6];

    float* aggp = (float*)d_out;                          // [N,64]
    float* outp = aggp + (size_t)NNODES * 64;             // [E,64]

    // ws layout
    short*    xb   = (short*)d_ws;                        // 6,400,000 B
    short*    wpk  = (short*)((char*)d_ws + 6400000);     //   114,688 B
    unsigned* meta = (unsigned*)((char*)d_ws + 6514688);
    unsigned* cnt    = meta;                              // [50000]
    unsigned* cur    = meta + 50000;                      // [50000]
    unsigned* done   = meta + 100000;                     // [1]
    unsigned* offs   = meta + 100002;                     // [50001] (8B-aligned base)
    unsigned* bsum   = meta + 150016;                     // [49]
    unsigned* elist  = meta + 150144;                     // [800000]   -> 950144
    uint2*    rc2    = (uint2*)(meta + 950144);           // [800000]u2 -> 2550144
    unsigned* outcsr = meta + 2550144;                    // [E*32] = 102.4 MB

    const size_t NEED = 6514688ULL + 2550144ULL * 4ULL + 102400000ULL;  // ~119.1 MB
    const bool big = ws_size >= NEED;

    // zero cnt + cur + done in one memset (contiguous 100002 dwords)
    (void)hipMemsetAsync(cnt, 0, 100002 * sizeof(unsigned), stream);
    prep_all<<<6410, 256, 0, stream>>>(x, xb, W1, W2, wpk, ei, cnt);
    csr_scan1<<<49, 1024, 0, stream>>>(cnt, offs, bsum, done);
    csr_scan3<<<49, 1024, 0, stream>>>(cnt, offs, bsum);
    csr_place<<<NEDGES / 256, 256, 0, stream>>>(ei, offs, cur, elist,
                                                big ? rc2 : (uint2*)nullptr);
    if (big) {
        edgeconv_csr<<<NBLK, 512, 0, stream>>>(xb, ea, wpk, b1, b2, elist, rc2,
                                               outp, outcsr);
        agg_csr<<<(NNODES + 3) / 4, 256, 0, stream>>>(offs, outcsr, aggp);
    } else {
        edgeconv_orig<<<NBLK, 512, 0, stream>>>(xb, ei, ea, wpk, b1, b2, outp);
        agg_list<<<(NNODES + 3) / 4, 256, 0, stream>>>(offs, elist, outp, aggp);
    }
}

// Round 22
// 289.248 us; speedup vs baseline: 1.0703x; 1.0703x over previous
//
#include <hip/hip_runtime.h>
#include <hip/hip_bf16.h>
#include <math.h>

#define NNODES 50000
#define NEDGES 800000
#define CHUNKS (NEDGES / 64)     // 12500 chunks of 64 edges (original order)
#define NBLK 256
#define GWAVES (NBLK * 8)        // 2048 persistent waves (512-thr blocks)

using short8 = __attribute__((ext_vector_type(8))) short;   // 8 bf16 = 4 VGPRs
using f32x4  = __attribute__((ext_vector_type(4))) float;
using f32x16 = __attribute__((ext_vector_type(16))) float;  // 32x32 MFMA acc
using u32x4  = __attribute__((ext_vector_type(4))) unsigned;

// fp32 -> bf16 RNE
__device__ __forceinline__ short f2b(float v) {
    return __builtin_bit_cast(short, __float2bfloat16(v));
}
// pack 2 fp32 -> 1 dword of 2 bf16 (lo = a)
__device__ __forceinline__ unsigned cvt2(float a, float b) {
    return (unsigned)(unsigned short)f2b(a) | ((unsigned)(unsigned short)f2b(b) << 16);
}

// ---- merged prep: x->bf16, W pack, CSR count ----
__global__ void prep_all(const float* __restrict__ x, short* __restrict__ xb,
                         const float* __restrict__ W1, const float* __restrict__ W2,
                         short* __restrict__ wpk, const int* __restrict__ ei,
                         unsigned* __restrict__ cnt)
{
    int b = blockIdx.x;
    if (b < 3125) {                       // x -> bf16 (800000 float4 groups)
        int i = b * 256 + threadIdx.x;
        float4 v = reinterpret_cast<const float4*>(x)[i];
        short4 o;
        o.x = f2b(v.x); o.y = f2b(v.y); o.z = f2b(v.z); o.w = f2b(v.w);
        reinterpret_cast<short4*>(xb)[i] = o;
    } else if (b < 6250) {                // CSR degree count
        int e = (b - 3125) * 256 + threadIdx.x;
        atomicAdd(&cnt[ei[e]], 1u);
    } else {                              // weight pack (32x32x16 A-frag order)
        int i = (b - 6250) * 256 + threadIdx.x;
        if (i < 40960) {                  // W1 [k<160][n<256]
            int k = i >> 8, n = i & 255;
            int lane = (n & 31) + (((k >> 3) & 1) << 5);
            wpk[(((n >> 5) * 10 + (k >> 4)) * 64 + lane) * 8 + (k & 7)] = f2b(W1[i]);
        }
        if (i < 16384) {                  // W2 [k<256][n<64]
            int k = i >> 6, n = i & 63;
            int lane = (n & 31) + (((k >> 3) & 1) << 5);
            wpk[40960 + (((n >> 5) * 16 + (k >> 4)) * 64 + lane) * 8 + (k & 7)] = f2b(W2[i]);
        }
    }
}

// ---- CSR scan/place (proven) ----
__global__ __launch_bounds__(1024)
void csr_scan1(const unsigned* __restrict__ cnt, unsigned* __restrict__ offs,
               unsigned* __restrict__ bsum) {
    __shared__ unsigned sbuf[1024];
    int t = threadIdx.x, i = blockIdx.x * 1024 + t;
    unsigned v = (i < NNODES) ? cnt[i] : 0u;
    sbuf[t] = v;
    __syncthreads();
    for (int off = 1; off < 1024; off <<= 1) {
        unsigned add = (t >= off) ? sbuf[t - off] : 0u;
        __syncthreads();
        sbuf[t] += add;
        __syncthreads();
    }
    if (i < NNODES) offs[i] = sbuf[t];
    if (t == 1023) bsum[blockIdx.x] = sbuf[1023];
}

__global__ void csr_scan2(unsigned* __restrict__ bsum) {
    int t = threadIdx.x;
    unsigned v = (t < 49) ? bsum[t] : 0u;
    unsigned orig = v;
    for (int off = 1; off < 64; off <<= 1) {
        unsigned n = __shfl_up(v, off, 64);
        if (t >= off) v += n;
    }
    if (t < 49) bsum[t] = v - orig;
}

__global__ __launch_bounds__(1024)
void csr_scan3(const unsigned* __restrict__ cnt, unsigned* __restrict__ offs,
               const unsigned* __restrict__ bsum) {
    int i = blockIdx.x * 1024 + threadIdx.x;
    if (i < NNODES)       offs[i] = offs[i] - cnt[i] + bsum[blockIdx.x];
    else if (i == NNODES) offs[i] = NEDGES;
}

__global__ void csr_place(const int* __restrict__ ei, const unsigned* __restrict__ offs,
                          unsigned* __restrict__ cur, unsigned* __restrict__ elist) {
    int e = blockIdx.x * 256 + threadIdx.x;
    if (e < NEDGES) {
        int r = ei[e];
        unsigned p = offs[r] + atomicAdd(&cur[r], 1u);
        elist[p] = (unsigned)e;
    }
}

// ---- main MLP: M=64/wave (2 edge groups), 512-thr blocks, 256-reg tier ----
// launch_bounds(512,2): 2 waves/SIMD min -> 256-reg budget, no spills for the
// ~226-reg live set (fx[2][10]=80V + acc1[2]=32A + acc2[2][2]=64A + addr).
// W1/W2 LDS reads amortized over 2x edges; GEMM1 has 2 indep MFMA chains.
__global__ __launch_bounds__(512, 2)
void edgeconv_main(const short* __restrict__ xb, const int* __restrict__ ei,
                   const float* __restrict__ ea, const short* __restrict__ wpk,
                   const float* __restrict__ b1, const float* __restrict__ b2,
                   float* __restrict__ outbuf)
{
    __shared__ short wlds[57344];        // 112 KB: W1 frags (80K) + W2 frags (32K)

    for (int i = threadIdx.x; i < 7168; i += 512)
        reinterpret_cast<short8*>(wlds)[i] = reinterpret_cast<const short8*>(wpk)[i];
    __syncthreads();                     // only block-wide barrier

    const short* w1s = wlds;
    const short* w2s = wlds + 40960;
    const int lane = threadIdx.x & 63;
    const int wave = threadIdx.x >> 6;
    const int l32 = lane & 31, hi = lane >> 5;
    const int gw = blockIdx.x * 8 + wave;

    // prime the index pipeline (2 edge groups)
    int r0 = 0, r1 = 0, c0 = 0, c1 = 0;
    {
        int ea0 = gw * 64 + l32, ea1 = gw * 64 + 32 + l32;
        r0 = ei[ea0]; c0 = ei[NEDGES + ea0];
        r1 = ei[ea1]; c1 = ei[NEDGES + ea1];
    }

    for (int c = gw; c < CHUNKS; c += GWAVES) {
        // ---- prefetch next chunk's indices ----
        int cn = c + GWAVES;
        int r0n = 0, r1n = 0, c0n = 0, c1n = 0;
        if (cn < CHUNKS) {
            int ea0 = cn * 64 + l32, ea1 = cn * 64 + 32 + l32;
            r0n = ei[ea0]; c0n = ei[NEDGES + ea0];
            r1n = ei[ea1]; c1n = ei[NEDGES + ea1];
        }

        // ---- gather B-fragments for both groups: k = ks*16 + hi*8 + j ----
        short8 fx[2][10];
        #pragma unroll
        for (int g = 0; g < 2; ++g) {
            const int rr = g ? r1 : r0, cg = g ? c1 : c0;
            const int e = c * 64 + g * 32 + l32;
            #pragma unroll
            for (int ks = 0; ks < 4; ++ks)
                fx[g][ks] = *reinterpret_cast<const short8*>(xb + rr * 64 + ks * 16 + hi * 8);
            #pragma unroll
            for (int ks = 0; ks < 4; ++ks)
                fx[g][4 + ks] = *reinterpret_cast<const short8*>(xb + cg * 64 + ks * 16 + hi * 8);
            #pragma unroll
            for (int ks = 0; ks < 2; ++ks) {
                const float4* p = reinterpret_cast<const float4*>(ea + (size_t)e * 32 + ks * 16 + hi * 8);
                float4 a = p[0], b = p[1];
                u32x4 uu;
                uu[0] = cvt2(a.x, a.y); uu[1] = cvt2(a.z, a.w);
                uu[2] = cvt2(b.x, b.y); uu[3] = cvt2(b.z, b.w);
                fx[g][8 + ks] = __builtin_bit_cast(short8, uu);
            }
        }

        // ---- acc2 init = b2 ----
        f32x16 acc2[2][2];   // [t2][g]
        #pragma unroll
        for (int t2 = 0; t2 < 2; ++t2)
            #pragma unroll
            for (int gg = 0; gg < 4; ++gg) {
                float4 bb = *reinterpret_cast<const float4*>(b2 + t2 * 32 + gg * 8 + hi * 4);
                #pragma unroll
                for (int g = 0; g < 2; ++g) {
                    acc2[t2][g][gg * 4 + 0] = bb.x; acc2[t2][g][gg * 4 + 1] = bb.y;
                    acc2[t2][g][gg * 4 + 2] = bb.z; acc2[t2][g][gg * 4 + 3] = bb.w;
                }
            }

        #pragma unroll 1
        for (int t = 0; t < 8; ++t) {    // 8 H-tiles of 32 cols
            // ---- GEMM1: one W1 frag feeds 2 independent chains ----
            f32x16 acc1[2];
            #pragma unroll
            for (int gg = 0; gg < 4; ++gg) {
                float4 bb = *reinterpret_cast<const float4*>(b1 + t * 32 + gg * 8 + hi * 4);
                #pragma unroll
                for (int g = 0; g < 2; ++g) {
                    acc1[g][gg * 4 + 0] = bb.x; acc1[g][gg * 4 + 1] = bb.y;
                    acc1[g][gg * 4 + 2] = bb.z; acc1[g][gg * 4 + 3] = bb.w;
                }
            }
            #pragma unroll
            for (int ks = 0; ks < 10; ++ks) {
                short8 wf = *reinterpret_cast<const short8*>(
                    w1s + ((t * 10 + ks) * 64 + lane) * 8);
                acc1[0] = __builtin_amdgcn_mfma_f32_32x32x16_bf16(wf, fx[0][ks], acc1[0], 0, 0, 0);
                acc1[1] = __builtin_amdgcn_mfma_f32_32x32x16_bf16(wf, fx[1][ks], acc1[1], 0, 0, 0);
            }
            // ---- ReLU + bf16 + permlane -> GEMM2 (W2 frags shared by groups) ----
            #pragma unroll
            for (int ksl = 0; ksl < 2; ++ksl) {
                int ks2 = t * 2 + ksl;
                short8 w20 = *reinterpret_cast<const short8*>(w2s + (ks2 * 64 + lane) * 8);
                short8 w21 = *reinterpret_cast<const short8*>(w2s + ((16 + ks2) * 64 + lane) * 8);
                #pragma unroll
                for (int g = 0; g < 2; ++g) {
                    int q0 = ksl * 8;
                    unsigned D0 = cvt2(fmaxf(acc1[g][q0 + 0], 0.f), fmaxf(acc1[g][q0 + 1], 0.f));
                    unsigned D1 = cvt2(fmaxf(acc1[g][q0 + 2], 0.f), fmaxf(acc1[g][q0 + 3], 0.f));
                    unsigned D2 = cvt2(fmaxf(acc1[g][q0 + 4], 0.f), fmaxf(acc1[g][q0 + 5], 0.f));
                    unsigned D3 = cvt2(fmaxf(acc1[g][q0 + 6], 0.f), fmaxf(acc1[g][q0 + 7], 0.f));
                    asm("v_permlane32_swap_b32 %0, %1" : "+v"(D0), "+v"(D2));
                    asm("v_permlane32_swap_b32 %0, %1" : "+v"(D1), "+v"(D3));
                    u32x4 bu; bu[0] = D0; bu[1] = D1; bu[2] = D2; bu[3] = D3;
                    short8 hb = __builtin_bit_cast(short8, bu);
                    acc2[0][g] = __builtin_amdgcn_mfma_f32_32x32x16_bf16(w20, hb, acc2[0][g], 0, 0, 0);
                    acc2[1][g] = __builtin_amdgcn_mfma_f32_32x32x16_bf16(w21, hb, acc2[1][g], 0, 0, 0);
                }
            }
        }

        // ---- epilogue: normal f32 out stores ----
        #pragma unroll
        for (int g = 0; g < 2; ++g) {
            const int e = c * 64 + g * 32 + l32;
            #pragma unroll
            for (int t2 = 0; t2 < 2; ++t2)
                #pragma unroll
                for (int gg = 0; gg < 4; ++gg) {
                    f32x4 v;
                    v[0] = acc2[t2][g][gg * 4 + 0]; v[1] = acc2[t2][g][gg * 4 + 1];
                    v[2] = acc2[t2][g][gg * 4 + 2]; v[3] = acc2[t2][g][gg * 4 + 3];
                    *reinterpret_cast<f32x4*>(outbuf + (size_t)e * 64 + t2 * 32 + gg * 8 + hi * 4) = v;
                }
        }

        r0 = r0n; r1 = r1n; c0 = c0n; c1 = c1n;
    }
}

// ---- aggregate: one wave per node, lane = column, 8-deep ILP max walk ----
__global__ __launch_bounds__(256)
void agg_list(const unsigned* __restrict__ offs, const unsigned* __restrict__ elist,
              const float* __restrict__ outbuf, float* __restrict__ agg)
{
    const int wave = threadIdx.x >> 6, lane = threadIdx.x & 63;
    const int node = blockIdx.x * 4 + wave;
    if (node >= NNODES) return;
    const unsigned s = offs[node], eend = offs[node + 1];
    float m0 = -INFINITY, m1 = -INFINITY, m2 = -INFINITY, m3 = -INFINITY;
    float m4 = -INFINITY, m5 = -INFINITY, m6 = -INFINITY, m7 = -INFINITY;
    unsigned p = s;
    for (; p + 8 <= eend; p += 8) {
        float a = outbuf[(size_t)elist[p + 0] * 64 + lane];
        float b = outbuf[(size_t)elist[p + 1] * 64 + lane];
        float c = outbuf[(size_t)elist[p + 2] * 64 + lane];
        float d = outbuf[(size_t)elist[p + 3] * 64 + lane];
        float e = outbuf[(size_t)elist[p + 4] * 64 + lane];
        float f = outbuf[(size_t)elist[p + 5] * 64 + lane];
        float g = outbuf[(size_t)elist[p + 6] * 64 + lane];
        float h = outbuf[(size_t)elist[p + 7] * 64 + lane];
        m0 = fmaxf(m0, a); m1 = fmaxf(m1, b); m2 = fmaxf(m2, c); m3 = fmaxf(m3, d);
        m4 = fmaxf(m4, e); m5 = fmaxf(m5, f); m6 = fmaxf(m6, g); m7 = fmaxf(m7, h);
    }
    for (; p < eend; ++p) m0 = fmaxf(m0, outbuf[(size_t)elist[p] * 64 + lane]);
    float m = fmaxf(fmaxf(fmaxf(m0, m1), fmaxf(m2, m3)),
                    fmaxf(fmaxf(m4, m5), fmaxf(m6, m7)));
    agg[(size_t)node * 64 + lane] = (s == eend) ? 0.0f : m;
}

extern "C" void kernel_launch(void* const* d_in, const int* in_sizes, int n_in,
                              void* d_out, int out_size, void* d_ws, size_t ws_size,
                              hipStream_t stream)
{
    const float* x  = (const float*)d_in[0];
    const int*   ei = (const int*)d_in[1];
    const float* ea = (const float*)d_in[2];
    const float* W1 = (const float*)d_in[3];
    const float* b1 = (const float*)d_in[4];
    const float* W2 = (const float*)d_in[5];
    const float* b2 = (const float*)d_in[6];

    float* aggp = (float*)d_out;                          // [N,64]
    float* outp = aggp + (size_t)NNODES * 64;             // [E,64]

    // ws layout (~10.3 MB, proven)
    short*    xb   = (short*)d_ws;                        // 6,400,000 B bf16 x
    short*    wpk  = (short*)((char*)d_ws + 6400000);     //   114,688 B packed W1+W2
    unsigned* meta = (unsigned*)((char*)d_ws + 6514688);
    unsigned* cnt   = meta;                               // [50000]
    unsigned* cur   = meta + 50000;                       // [50000]
    unsigned* offs  = meta + 100000;                      // [50001]
    unsigned* bsum  = meta + 150016;                      // [49]
    unsigned* elist = meta + 150144;                      // [800000]

    (void)hipMemsetAsync(cnt, 0, 100000 * sizeof(unsigned), stream);   // cnt + cur
    prep_all<<<6410, 256, 0, stream>>>(x, xb, W1, W2, wpk, ei, cnt);
    csr_scan1<<<49, 1024, 0, stream>>>(cnt, offs, bsum);
    csr_scan2<<<1, 64, 0, stream>>>(bsum);
    csr_scan3<<<49, 1024, 0, stream>>>(cnt, offs, bsum);
    csr_place<<<NEDGES / 256, 256, 0, stream>>>(ei, offs, cur, elist);
    edgeconv_main<<<NBLK, 512, 0, stream>>>(xb, ei, ea, wpk, b1, b2, outp);
    agg_list<<<(NNODES + 3) / 4, 256, 0, stream>>>(offs, elist, outp, aggp);
}